// Round 4
// baseline (178.740 us; speedup 1.0000x reference)
//
#include <hip/hip_runtime.h>

// Problem: B=64, K=17, H=128, W=128, RATIO=0.25, SIGMA=2.0
constexpr int   HW     = 16384;
constexpr int   NSLICE = 1088;          // 64*17
constexpr int   GTMAX  = 4096;          // pxl_num; kthvalue rank 12288 from bottom
constexpr float LO0    = 0.735f;        // static bracket around 0.75-quantile of U(0,1)
constexpr float HI0    = 0.770f;        // runtime-validated; exact fallback otherwise
constexpr int   SLOTS  = 10;            // per-thread stash (mean 1.12, P(ovf/launch)~2e-2)
constexpr int   SSTR   = 11;            // stash stride pad (breaks LDS bank conflicts)
constexpr int   BINS   = 1024;          // counting-refinement buckets
constexpr float BSCALE = (float)BINS / (HI0 - LO0);

constexpr int NT   = 512;               // 8 waves per block
constexpr int V4   = 8;                 // float4 per thread per array
constexpr int NBLK = 256;               // persistent: 1 block per CU
constexpr int XTRA = NSLICE - 4 * NBLK; // 64 blocks take a 5th slice

__device__ __forceinline__ int bucket_of(float x) {
    int b = (int)((x - LO0) * BSCALE);  // monotone on (LO0, HI0]
    return b < 0 ? 0 : (b > BINS - 1 ? BINS - 1 : b);
}

// Persistent fused kernel: each block pipelines 4-5 slices.
// Per slice: [issue pred loads] pass1(tgt regs) [issue next tgt loads]
//            selection (loads in flight) pass2(pred regs).
__global__ __launch_bounds__(NT, 2) void wreg_persistent(
    const float* __restrict__ tgt, const float* __restrict__ pred,
    float* __restrict__ partial)
{
    __shared__ int   hist[BINS];          // 4 KB
    __shared__ float sval[NT * SSTR];     // 22.5 KB per-thread stash
    __shared__ float redf[8];
    __shared__ int   redi[8];
    __shared__ int   whi[8], wwin[8], wovf[8], wcnt[8], wtot[8];
    __shared__ float cands[64];
    __shared__ int   s_nc, s_bstar, s_above;
    __shared__ float s_th;

    const int t = threadIdx.x, lane = t & 63, wid = t >> 6;
    const int b = blockIdx.x;
    const int nr = (b < XTRA) ? 5 : 4;
    const int sbase = t * SSTR;

    float acc = 0.f;

    // prologue: issue tgt loads for slice 0
    float4 va[V4];
    {
        const float4* t4p = reinterpret_cast<const float4*>(tgt) + (size_t)b * (HW / 4);
        #pragma unroll
        for (int j = 0; j < V4; ++j) va[j] = t4p[j * NT + t];
    }

    for (int r = 0; r < nr; ++r) {
        const int scur = (r < 4) ? (b + r * NBLK) : (4 * NBLK + b);
        const float4* t4c = reinterpret_cast<const float4*>(tgt)  + (size_t)scur * (HW / 4);
        const float4* p4c = reinterpret_cast<const float4*>(pred) + (size_t)scur * (HW / 4);

        // issue pred loads now — consumed only in pass2, hides under pass1+selection
        float4 pv[V4];
        #pragma unroll
        for (int j = 0; j < V4; ++j) pv[j] = p4c[j * NT + t];

        if (t == 0) s_nc = 0;
        #pragma unroll
        for (int i = t; i < BINS; i += NT) hist[i] = 0;
        // (ordering: zeroing/reset above is separated from this iteration's first
        //  use by the post-reduce __syncthreads; separated from the previous
        //  iteration's last reads by the pre-pass2 __syncthreads.)

        // ---- Pass 1: consume tgt regs -> argmax, hi-bits, window bits + stash ----
        float bmax = -1.f; int bmi = 0; int myn = 0;
        unsigned hib = 0u, wib = 0u;
        #pragma unroll
        for (int j = 0; j < V4; ++j) {
            const int base = (j * NT + t) * 4;
            float a[4] = {va[j].x, va[j].y, va[j].z, va[j].w};
            #pragma unroll
            for (int c = 0; c < 4; ++c) {
                float x = a[c];
                if (x > bmax) { bmax = x; bmi = base + c; }   // per-thread idx increasing
                hib |= (unsigned)(x > HI0) << (j * 4 + c);
                if (x > LO0 && x <= HI0) {
                    wib |= 1u << (j * 4 + c);
                    if (myn < SLOTS) sval[sbase + myn] = x;
                    ++myn;
                }
            }
        }
        const int mynv = myn > SLOTS ? SLOTS : myn;

        // va regs now dead: issue next slice's tgt loads (hide under selection+pass2)
        if (r + 1 < nr) {
            const int snext = (r + 1 < 4) ? (b + (r + 1) * NBLK) : (4 * NBLK + b);
            const float4* t4n = reinterpret_cast<const float4*>(tgt) + (size_t)snext * (HW / 4);
            #pragma unroll
            for (int j = 0; j < V4; ++j) va[j] = t4n[j * NT + t];
        }

        // ---- Combined block reduce: argmax + #(>HI0) + window count + overflow ----
        {
            float am = bmax; int ai = bmi;
            int rh = __popc(hib), rw = myn, ro = (myn > SLOTS) ? 1 : 0;
            #pragma unroll
            for (int off = 32; off > 0; off >>= 1) {
                float ov = __shfl_down(am, off); int ai2 = __shfl_down(ai, off);
                int o1 = __shfl_down(rh, off), o2 = __shfl_down(rw, off), o3 = __shfl_down(ro, off);
                if (ov > am || (ov == am && ai2 < ai)) { am = ov; ai = ai2; }
                rh += o1; rw += o2; ro |= o3;
            }
            if (lane == 0) { redf[wid] = am; redi[wid] = ai; whi[wid] = rh; wwin[wid] = rw; wovf[wid] = ro; }
        }
        __syncthreads();   // orders hist zeroing + s_nc reset before use as well
        float mv = redf[0]; int mi = redi[0];
        int g_hi0 = 0, win = 0, anyovf = 0;
        #pragma unroll
        for (int w = 0; w < 8; ++w) {
            if (redf[w] > mv || (redf[w] == mv && redi[w] < mi)) { mv = redf[w]; mi = redi[w]; }
            g_hi0 += whi[w]; win += wwin[w]; anyovf |= wovf[w];
        }
        const int need = (GTMAX + 1) - g_hi0;   // rank-from-top within the window
        const bool valid = (!anyovf) && (g_hi0 <= GTMAX) && (need <= win);

        float th = 0.f;
        bool done = false;   // block-uniform throughout

        if (valid) {
            // ---- Counting refinement: histogram stash, suffix-scan, exact tiny rank ----
            for (int k = 0; k < mynv; ++k)
                atomicAdd(&hist[bucket_of(sval[sbase + k])], 1);
            __syncthreads();
            const int h0 = hist[2 * t], h1 = hist[2 * t + 1];
            const int lsum = h0 + h1;
            int incl = lsum;                        // wave suffix-inclusive scan
            #pragma unroll
            for (int off = 1; off < 64; off <<= 1) {
                int v = __shfl_down(incl, off);
                incl += (lane + off < 64) ? v : 0;
            }
            if (lane == 0) wtot[wid] = incl;        // wave total
            __syncthreads();
            int suf = incl - lsum;                  // count in strictly-higher buckets (my wave)
            #pragma unroll
            for (int w = 0; w < 8; ++w) suf += (w > wid) ? wtot[w] : 0;
            int running = suf;                      // above bucket 2t+1
            if (running < need && need <= running + h1) { s_bstar = 2 * t + 1; s_above = running; }
            running += h1;                          // above bucket 2t
            if (running < need && need <= running + h0) { s_bstar = 2 * t;     s_above = running; }
            __syncthreads();
            const int bstar = s_bstar, above = s_above;
            const int cnum = hist[bstar];           // block-uniform
            if (cnum <= 64) {
                for (int k = 0; k < mynv; ++k) {
                    float x = sval[sbase + k];
                    if (bucket_of(x) == bstar) { int pos = atomicAdd(&s_nc, 1); cands[pos] = x; }
                }
                __syncthreads();
                const int m = s_nc;                 // == cnum, usually 1-2
                for (int i = t; i < m; i += NT) {
                    float ci = cands[i];
                    int gt = 0, eq = 0;
                    for (int j2 = 0; j2 < m; ++j2) {
                        float cj = cands[j2];
                        gt += (cj > ci) ? 1 : 0; eq += (cj == ci) ? 1 : 0;
                    }
                    int gg = g_hi0 + above + gt;
                    if (gg <= GTMAX && gg + eq >= GTMAX + 1) s_th = ci;
                }
                __syncthreads();
                th = s_th;
                done = true;
            }
        }
        const bool fb = !done;
        if (fb) {
            // ---- Exact fallback (rare): value bisection re-reading this slice (cache-warm) ----
            float lo = -1.0f, hiv = mv;
            int g_lo = HW, g_hiC = 0;
            bool degen = false;
            while (g_lo - g_hiC > 48) {
                float mid = 0.5f * (lo + hiv);
                if (!(mid > lo && mid < hiv)) { degen = true; break; }
                int cnt = 0;
                for (int j = 0; j < V4; ++j) {
                    float4 v = t4c[j * NT + t];
                    cnt += (v.x > mid) + (v.y > mid) + (v.z > mid) + (v.w > mid);
                }
                #pragma unroll
                for (int off = 32; off > 0; off >>= 1) cnt += __shfl_down(cnt, off);
                if (lane == 0) wcnt[wid] = cnt;
                __syncthreads();
                int g = 0;
                #pragma unroll
                for (int w = 0; w < 8; ++w) g += wcnt[w];
                __syncthreads();
                if (g >= GTMAX + 1) { lo = mid; g_lo = g; }
                else                { hiv = mid; g_hiC = g; }
            }
            if (degen) th = hiv;
            else {
                if (t == 0) s_nc = 0;
                __syncthreads();
                for (int j = 0; j < V4; ++j) {
                    float4 v = t4c[j * NT + t];
                    float a[4] = {v.x, v.y, v.z, v.w};
                    for (int c2 = 0; c2 < 4; ++c2) {
                        float x = a[c2];
                        if (x > lo && x <= hiv) { int pos = atomicAdd(&s_nc, 1); if (pos < 64) cands[pos] = x; }
                    }
                }
                __syncthreads();
                int m = s_nc; m = m > 64 ? 64 : m;
                for (int i = t; i < m; i += NT) {
                    float ci = cands[i];
                    int gt = 0, eq = 0;
                    for (int j2 = 0; j2 < m; ++j2) {
                        float cj = cands[j2];
                        gt += (cj > ci) ? 1 : 0; eq += (cj == ci) ? 1 : 0;
                    }
                    int gg = g_hiC + gt;
                    if (gg <= GTMAX && gg + eq >= GTMAX + 1) s_th = ci;
                }
                __syncthreads();
                th = s_th;
            }
        }

        // ---- Pass 2: consume pred regs; mask from hi-bits + stash pops; Gaussian inline.
        // g = exp(-d2/8) only within the 31x31 box (outside g<=1.3e-14; error ~1e-11).
        const int cyi = mi >> 7, cxi = mi & 127;
        if (!fb) {
            int k = 0;
            #pragma unroll
            for (int j = 0; j < V4; ++j) {
                const int base = (j * NT + t) * 4;
                float ap[4] = {pv[j].x, pv[j].y, pv[j].z, pv[j].w};
                #pragma unroll
                for (int c = 0; c < 4; ++c) {
                    bool m = (hib >> (j * 4 + c)) & 1u;
                    if ((wib >> (j * 4 + c)) & 1u) { float x = sval[sbase + k]; ++k; m = (x > th); }
                    if (m) {
                        const int idx = base + c;
                        const int dy = (idx >> 7) - cyi, dx = (idx & 127) - cxi;
                        float p = ap[c];
                        if (dy >= -15 && dy <= 15 && dx >= -15 && dx <= 15) {
                            float g = __expf((float)(dy * dy + dx * dx) * -0.125f);
                            float d = p - g;
                            acc += d * d;
                        } else {
                            acc += p * p;
                        }
                    }
                }
            }
        } else {
            for (int j = 0; j < V4; ++j) {
                float4 tv = t4c[j * NT + t];
                const int base = (j * NT + t) * 4;
                float at[4] = {tv.x, tv.y, tv.z, tv.w};
                float ap[4] = {pv[j].x, pv[j].y, pv[j].z, pv[j].w};
                for (int c = 0; c < 4; ++c) {
                    if (at[c] > th) {
                        const int idx = base + c;
                        const int dy = (idx >> 7) - cyi, dx = (idx & 127) - cxi;
                        float p = ap[c];
                        if (dy >= -15 && dy <= 15 && dx >= -15 && dx <= 15) {
                            float g = __expf((float)(dy * dy + dx * dx) * -0.125f);
                            float d = p - g;
                            acc += d * d;
                        } else {
                            acc += p * p;
                        }
                    }
                }
            }
        }
        // loop back: next pass1 waits on va (in flight since before selection)
    }

    // ---- Final block reduce of per-thread acc across all owned slices ----
    __syncthreads();                 // guard redf reuse
    #pragma unroll
    for (int off = 32; off > 0; off >>= 1) acc += __shfl_down(acc, off);
    if (lane == 0) redf[wid] = acc;
    __syncthreads();
    if (t == 0) {
        float s = 0.f;
        #pragma unroll
        for (int w = 0; w < 8; ++w) s += redf[w];
        partial[b] = s;
    }
}

__global__ __launch_bounds__(256) void wreg_final(
    const float* __restrict__ partial, float* __restrict__ out)
{
    __shared__ float red[4];
    const int t = threadIdx.x;
    float s = partial[t];
    #pragma unroll
    for (int off = 32; off > 0; off >>= 1) s += __shfl_down(s, off);
    if ((t & 63) == 0) red[t >> 6] = s;
    __syncthreads();
    if (t == 0)
        out[0] = ((red[0] + red[1]) + (red[2] + red[3]))
                 * (1.0f / ((float)GTMAX * (float)NSLICE));   // / pxl_num / (B*K)
}

extern "C" void kernel_launch(void* const* d_in, const int* in_sizes, int n_in,
                              void* d_out, int out_size, void* d_ws, size_t ws_size,
                              hipStream_t stream)
{
    const float* pred = (const float*)d_in[0];   // "output" in reference
    const float* tgt  = (const float*)d_in[1];   // "target"
    float* partial = (float*)d_ws;               // 256 floats scratch
    float* out     = (float*)d_out;

    wreg_persistent<<<NBLK, NT, 0, stream>>>(tgt, pred, partial);
    wreg_final<<<1, 256, 0, stream>>>(partial, out);
}

// Round 5
// 171.259 us; speedup vs baseline: 1.0437x; 1.0437x over previous
//
#include <hip/hip_runtime.h>

// Problem: B=64, K=17, H=128, W=128, RATIO=0.25, SIGMA=2.0
constexpr int   HW     = 16384;
constexpr int   NT     = 512;            // threads per block; 1 block per slice
constexpr int   NWV    = 8;              // waves per block
constexpr int   V4     = 8;              // float4 groups per thread (32 elems/thread)
constexpr int   GTMAX  = 4096;           // #(v > thresh) for kthvalue rank 12288
constexpr int   NSLICE = 1088;           // 64*17
constexpr int   SLOTS  = 10;             // per-thread stash (mean 1.12, P(ovf/launch)~2e-2)
constexpr int   SSTR   = 11;             // stash stride pad
constexpr int   BINS   = 1024;           // counting-refinement buckets
constexpr float LO0    = 0.735f;         // static bracket around 0.75-quantile of U(0,1)
constexpr float HI0    = 0.770f;         // runtime-validated; exact fallback otherwise
constexpr float BSCALE = (float)BINS / (HI0 - LO0);

__device__ __forceinline__ int bucket_of(float x) {
    int b = (int)((x - LO0) * BSCALE);   // monotone in x on (LO0, HI0]
    return b < 0 ? 0 : (b > BINS - 1 ? BINS - 1 : b);
}

// launch_bounds (NT,4): VGPR cap 128 so va[8]+pv[8] (64 data VGPRs) stay live.
// Round-0's (NT,6) capped at 85 VGPR -> compiler serialized the bursts (VGPR_Count=40).
__global__ __launch_bounds__(NT, 4) void wreg_fused(
    const float* __restrict__ pred,
    const float* __restrict__ tgt,
    float* __restrict__ partial)
{
    __shared__ int   hist[BINS];          // 4 KB
    __shared__ float sval[NT * SSTR];     // 22.5 KB
    __shared__ float redf[NWV];
    __shared__ int   redi[NWV];
    __shared__ int   whi[NWV], wwin[NWV], wovf[NWV], wcnt[NWV], wtot[NWV];
    __shared__ float cands[64];
    __shared__ int   s_nc, s_bstar, s_above;
    __shared__ float s_th;

    const int t = threadIdx.x, lane = t & 63, wid = t >> 6;
    const int bid = blockIdx.x;
    const float4* t4 = reinterpret_cast<const float4*>(tgt)  + (size_t)bid * (HW / 4);
    const float4* p4 = reinterpret_cast<const float4*>(pred) + (size_t)bid * (HW / 4);
    const int sbase = t * SSTR;

    // ---- Issue BOTH bursts up-front: 16 float4 loads in flight per thread ----
    float4 va[V4], pv[V4];
    #pragma unroll
    for (int j = 0; j < V4; ++j) va[j] = t4[j * NT + t];
    #pragma unroll
    for (int j = 0; j < V4; ++j) pv[j] = p4[j * NT + t];

    // hist zeroing overlaps the in-flight loads
    #pragma unroll
    for (int i = t; i < BINS; i += NT) hist[i] = 0;
    if (t == 0) s_nc = 0;

    // ---- Pass 1: consume tgt regs ----
    float bmax = -1.f; int bmi = 0;
    int myn = 0;
    unsigned hib = 0u, wib = 0u;          // 1 bit per element (32 elems/thread)
    #pragma unroll
    for (int j = 0; j < V4; ++j) {
        const int base = (j * NT + t) * 4;
        float a[4] = {va[j].x, va[j].y, va[j].z, va[j].w};
        #pragma unroll
        for (int c = 0; c < 4; ++c) {
            float x = a[c];
            if (x > bmax) { bmax = x; bmi = base + c; }   // per-thread idx increasing
            hib |= (unsigned)(x > HI0) << (j * 4 + c);
            if (x > LO0 && x <= HI0) {
                wib |= 1u << (j * 4 + c);
                if (myn < SLOTS) sval[sbase + myn] = x;
                ++myn;
            }
        }
    }
    const int mynv = myn > SLOTS ? SLOTS : myn;

    // ---- One combined block reduce: argmax + #(>HI0) + window count + overflow ----
    {
        float am = bmax; int ai = bmi;
        int rh = __popc(hib), rw = myn, ro = (myn > SLOTS) ? 1 : 0;
        #pragma unroll
        for (int off = 32; off > 0; off >>= 1) {
            float ov = __shfl_down(am, off); int ai2 = __shfl_down(ai, off);
            int o1 = __shfl_down(rh, off), o2 = __shfl_down(rw, off), o3 = __shfl_down(ro, off);
            if (ov > am || (ov == am && ai2 < ai)) { am = ov; ai = ai2; }
            rh += o1; rw += o2; ro |= o3;
        }
        if (lane == 0) { redf[wid] = am; redi[wid] = ai; whi[wid] = rh; wwin[wid] = rw; wovf[wid] = ro; }
    }
    __syncthreads();   // drains both bursts (the one intended BW wait); orders hist zeroing
    float mv = redf[0]; int mi = redi[0];
    int g_hi0 = 0, win = 0, anyovf = 0;
    #pragma unroll
    for (int w = 0; w < NWV; ++w) {
        if (redf[w] > mv || (redf[w] == mv && redi[w] < mi)) { mv = redf[w]; mi = redi[w]; }
        g_hi0 += whi[w]; win += wwin[w]; anyovf |= wovf[w];
    }
    const int need = (GTMAX + 1) - g_hi0;   // rank-from-top within the window
    const bool valid = (!anyovf) && (g_hi0 <= GTMAX) && (need <= win);

    float th = 0.f;
    bool done = false;   // block-uniform throughout

    if (valid) {
        // ---- Counting refinement: histogram stash, suffix-scan, exact tiny rank ----
        for (int k = 0; k < mynv; ++k)
            atomicAdd(&hist[bucket_of(sval[sbase + k])], 1);
        __syncthreads();
        const int h0 = hist[2 * t], h1 = hist[2 * t + 1];
        const int lsum = h0 + h1;
        int incl = lsum;                        // wave suffix-inclusive scan
        #pragma unroll
        for (int off = 1; off < 64; off <<= 1) {
            int v = __shfl_down(incl, off);
            incl += (lane + off < 64) ? v : 0;
        }
        if (lane == 0) wtot[wid] = incl;        // wave total
        __syncthreads();
        int suf = incl - lsum;                  // count in strictly-higher buckets (my wave)
        #pragma unroll
        for (int w = 0; w < NWV; ++w) suf += (w > wid) ? wtot[w] : 0;
        int running = suf;                      // above bucket 2t+1
        if (running < need && need <= running + h1) { s_bstar = 2 * t + 1; s_above = running; }
        running += h1;                          // above bucket 2t
        if (running < need && need <= running + h0) { s_bstar = 2 * t;     s_above = running; }
        __syncthreads();
        const int bstar = s_bstar, above = s_above;
        const int cnum = hist[bstar];           // block-uniform
        if (cnum <= 64) {
            for (int k = 0; k < mynv; ++k) {
                float x = sval[sbase + k];
                if (bucket_of(x) == bstar) { int pos = atomicAdd(&s_nc, 1); cands[pos] = x; }
            }
            __syncthreads();
            const int m = s_nc;                 // == cnum, usually 1-2
            for (int i = t; i < m; i += NT) {
                float ci = cands[i];
                int gt = 0, eq = 0;
                for (int j2 = 0; j2 < m; ++j2) {
                    float cj = cands[j2];
                    gt += (cj > ci) ? 1 : 0; eq += (cj == ci) ? 1 : 0;
                }
                int gg = g_hi0 + above + gt;
                if (gg <= GTMAX && gg + eq >= GTMAX + 1) s_th = ci;
            }
            __syncthreads();
            th = s_th;
            done = true;
        }
    }
    const bool fb = !done;
    if (fb) {
        // ---- Exact fallback (rare, ~2%/launch): value bisection re-reading tgt ----
        float lo = -1.0f, hi = mv;
        int g_lo = HW, g_hi = 0;
        bool degen = false;
        while (g_lo - g_hi > 48) {
            float mid = 0.5f * (lo + hi);
            if (!(mid > lo && mid < hi)) { degen = true; break; }
            int cnt = 0;
            for (int j = 0; j < V4; ++j) {
                float4 v = t4[j * NT + t];
                cnt += (v.x > mid) + (v.y > mid) + (v.z > mid) + (v.w > mid);
            }
            #pragma unroll
            for (int off = 32; off > 0; off >>= 1) cnt += __shfl_down(cnt, off);
            if (lane == 0) wcnt[wid] = cnt;
            __syncthreads();
            int g = 0;
            #pragma unroll
            for (int w = 0; w < NWV; ++w) g += wcnt[w];
            __syncthreads();
            if (g >= GTMAX + 1) { lo = mid; g_lo = g; }
            else                { hi = mid; g_hi = g; }
        }
        if (degen) th = hi;
        else {
            if (t == 0) s_nc = 0;
            __syncthreads();
            for (int j = 0; j < V4; ++j) {
                float4 v = t4[j * NT + t];
                float a[4] = {v.x, v.y, v.z, v.w};
                for (int c2 = 0; c2 < 4; ++c2) {
                    float x = a[c2];
                    if (x > lo && x <= hi) { int pos = atomicAdd(&s_nc, 1); if (pos < 64) cands[pos] = x; }
                }
            }
            __syncthreads();
            int m = s_nc; m = m > 64 ? 64 : m;
            for (int i = t; i < m; i += NT) {
                float ci = cands[i];
                int gt = 0, eq = 0;
                for (int j2 = 0; j2 < m; ++j2) {
                    float cj = cands[j2];
                    gt += (cj > ci) ? 1 : 0; eq += (cj == ci) ? 1 : 0;
                }
                int gg = g_hi + gt;
                if (gg <= GTMAX && gg + eq >= GTMAX + 1) s_th = ci;
            }
            __syncthreads();
            th = s_th;
        }
    }

    // ---- Pass 2: consume pred regs (loaded at entry); mask from hi-bits + stash pops.
    // g = exp(-d2/8) only within the 31x31 box (outside g<=1.3e-14; error ~1e-11).
    const int cyi = mi >> 7, cxi = mi & 127;
    float sum = 0.f;
    if (!fb) {
        int k = 0;
        #pragma unroll
        for (int j = 0; j < V4; ++j) {
            const int base = (j * NT + t) * 4;
            float ap[4] = {pv[j].x, pv[j].y, pv[j].z, pv[j].w};
            #pragma unroll
            for (int c = 0; c < 4; ++c) {
                bool m = (hib >> (j * 4 + c)) & 1u;
                if ((wib >> (j * 4 + c)) & 1u) { float x = sval[sbase + k]; ++k; m = (x > th); }
                if (m) {
                    const int idx = base + c;
                    const int dy = (idx >> 7) - cyi, dx = (idx & 127) - cxi;
                    float p = ap[c];
                    if (dy >= -15 && dy <= 15 && dx >= -15 && dx <= 15) {
                        float g = __expf((float)(dy * dy + dx * dx) * -0.125f);
                        float d = p - g;
                        sum += d * d;
                    } else {
                        sum += p * p;
                    }
                }
            }
        }
    } else {
        for (int j = 0; j < V4; ++j) {
            const int vi = j * NT + t;
            float4 tv = t4[vi];
            const int base = vi * 4;
            float at[4] = {tv.x, tv.y, tv.z, tv.w};
            float ap[4] = {pv[j].x, pv[j].y, pv[j].z, pv[j].w};
            for (int c = 0; c < 4; ++c) {
                if (at[c] > th) {
                    const int idx = base + c;
                    const int dy = (idx >> 7) - cyi, dx = (idx & 127) - cxi;
                    float p = ap[c];
                    if (dy >= -15 && dy <= 15 && dx >= -15 && dx <= 15) {
                        float g = __expf((float)(dy * dy + dx * dx) * -0.125f);
                        float d = p - g;
                        sum += d * d;
                    } else {
                        sum += p * p;
                    }
                }
            }
        }
    }

    // ---- Block reduce, one plain store ----
    #pragma unroll
    for (int off = 32; off > 0; off >>= 1) sum += __shfl_down(sum, off);
    __syncthreads();                 // redf reuse guard
    if (lane == 0) redf[wid] = sum;
    __syncthreads();
    if (t == 0) {
        float s = 0.f;
        #pragma unroll
        for (int w = 0; w < NWV; ++w) s += redf[w];
        partial[bid] = s;
    }
}

__global__ __launch_bounds__(256) void wreg_final(
    const float* __restrict__ partial, float* __restrict__ out)
{
    __shared__ float red[4];
    const int t = threadIdx.x;
    float s = 0.f;
    for (int i = t; i < NSLICE; i += 256) s += partial[i];
    #pragma unroll
    for (int off = 32; off > 0; off >>= 1) s += __shfl_down(s, off);
    if ((t & 63) == 0) red[t >> 6] = s;
    __syncthreads();
    if (t == 0)
        out[0] = ((red[0] + red[1]) + (red[2] + red[3]))
                 * (1.0f / ((float)(HW / 4) * (float)NSLICE));  // / pxl_num / (B*K)
}

extern "C" void kernel_launch(void* const* d_in, const int* in_sizes, int n_in,
                              void* d_out, int out_size, void* d_ws, size_t ws_size,
                              hipStream_t stream)
{
    const float* pred = (const float*)d_in[0];   // "output" in reference
    const float* tgt  = (const float*)d_in[1];   // "target"
    float* partial = (float*)d_ws;               // 1088 floats scratch
    float* out     = (float*)d_out;

    wreg_fused<<<NSLICE, NT, 0, stream>>>(pred, tgt, partial);
    wreg_final<<<1, 256, 0, stream>>>(partial, out);
}

// Round 7
// 167.051 us; speedup vs baseline: 1.0700x; 1.0252x over previous
//
#include <hip/hip_runtime.h>

// Problem: B=64, K=17, H=128, W=128, RATIO=0.25, SIGMA=2.0
constexpr int   HW     = 16384;
constexpr int   NT     = 512;            // threads per block; 1 block per slice
constexpr int   NWV    = 8;              // waves per block
constexpr int   V4     = 8;              // float4 groups per thread (32 elems/thread)
constexpr int   GTMAX  = 4096;           // #(v > thresh) for kthvalue rank 12288
constexpr int   NSLICE = 1088;           // 64*17
constexpr int   BINS   = 1024;           // counting-refinement buckets
constexpr float LO0    = 0.735f;         // static bracket around 0.75-quantile of U(0,1)
constexpr float HI0    = 0.770f;         // ~±5 sigma; exact LDS-bisection fallback otherwise
constexpr float BSCALE = (float)BINS / (HI0 - LO0);

__device__ __forceinline__ int bucket_of(float x) {
    int b = (int)((x - LO0) * BSCALE);   // monotone in x on (LO0, HI0]
    return b < 0 ? 0 : (b > BINS - 1 ? BINS - 1 : b);
}

// LDS: 64KB tile + 4KB hist + ~0.6KB misc = ~70KB -> 2 blocks/CU.
__global__ __launch_bounds__(NT, 2) void wreg_fused(
    const float* __restrict__ pred,
    const float* __restrict__ tgt,
    float* __restrict__ partial)
{
    __shared__ __align__(16) float tile[HW];   // whole tgt slice, staged via DMA
    __shared__ int   hist[BINS];
    __shared__ float redf[NWV];
    __shared__ int   redi[NWV], whi[NWV], wtot[NWV], wcnt[NWV];
    __shared__ float cands[64];
    __shared__ int   s_nc, s_bstar, s_above;
    __shared__ float s_th;

    const int t = threadIdx.x, lane = t & 63, wid = t >> 6;
    const int bid = blockIdx.x;
    const float*  ts    = tgt + (size_t)bid * HW;
    const float4* p4    = reinterpret_cast<const float4*>(pred) + (size_t)bid * (HW / 4);
    const float4* tile4 = reinterpret_cast<const float4*>(tile);

    // ---- Stage tgt slice into LDS: 8 x 1KB DMA per wave, zero VGPR cost ----
    // Each inst: 64 lanes x 16B; LDS dest = uniform base + lane*16 (HW rule).
    #pragma unroll
    for (int i = 0; i < 8; ++i) {
        const int inst = wid * 8 + i;              // 0..63, uniform per wave
        const char* gp = (const char*)ts + ((size_t)inst * 64 + lane) * 16;
        __builtin_amdgcn_global_load_lds(
            (__attribute__((address_space(1))) void*)gp,
            (__attribute__((address_space(3))) void*)(&tile[inst * 256]),
            16, 0, 0);
    }
    // overlap LDS housekeeping with the DMA flight
    for (int i = t; i < BINS; i += NT) hist[i] = 0;
    if (t == 0) s_nc = 0;
    asm volatile("s_waitcnt vmcnt(0)" ::: "memory");   // own wave's DMA done
    __syncthreads();                                    // B0: tile + hist ready

    // ---- Pass 1 (from LDS): argmax, #(>HI0), window histogram ----
    float bmax = -1.f; int bmi = 0; int hic = 0;
    #pragma unroll
    for (int j = 0; j < V4; ++j) {
        float4 v = tile4[j * NT + t];              // stride-1 lanes: conflict-free
        const int base = (j * NT + t) * 4;
        float a[4] = {v.x, v.y, v.z, v.w};
        #pragma unroll
        for (int c = 0; c < 4; ++c) {
            float x = a[c];
            if (x > bmax) { bmax = x; bmi = base + c; }   // per-thread idx increasing
            hic += (x > HI0) ? 1 : 0;
            if (x > LO0 && x <= HI0) atomicAdd(&hist[bucket_of(x)], 1);
        }
    }
    // issue pred loads now: fly under the selection chain (32 VGPRs, low pressure)
    float4 pv[V4];
    #pragma unroll
    for (int j = 0; j < V4; ++j) pv[j] = p4[j * NT + t];

    // ---- Combined block reduce: argmax (first-max tie) + #(>HI0) ----
    {
        float am = bmax; int ai = bmi; int rh = hic;
        #pragma unroll
        for (int off = 32; off > 0; off >>= 1) {
            float ov = __shfl_down(am, off); int ai2 = __shfl_down(ai, off);
            int o1 = __shfl_down(rh, off);
            if (ov > am || (ov == am && ai2 < ai)) { am = ov; ai = ai2; }
            rh += o1;
        }
        if (lane == 0) { redf[wid] = am; redi[wid] = ai; whi[wid] = rh; }
    }
    __syncthreads();   // B1: also orders pass-1 hist atomics before hist reads
    float mv = redf[0]; int mi = redi[0]; int g_hi0 = 0;
    #pragma unroll
    for (int w = 0; w < NWV; ++w) {
        if (redf[w] > mv || (redf[w] == mv && redi[w] < mi)) { mv = redf[w]; mi = redi[w]; }
        g_hi0 += whi[w];
    }
    const int need = (GTMAX + 1) - g_hi0;   // rank-from-top within the window

    // ---- Suffix scan of hist (thread t owns bins 2t, 2t+1) ----
    const int h0 = hist[2 * t], h1 = hist[2 * t + 1];
    const int lsum = h0 + h1;
    int incl = lsum;
    #pragma unroll
    for (int off = 1; off < 64; off <<= 1) {
        int v = __shfl_down(incl, off);
        incl += (lane + off < 64) ? v : 0;
    }
    if (lane == 0) wtot[wid] = incl;
    __syncthreads();   // B2
    int suf = incl - lsum, win = 0;
    #pragma unroll
    for (int w = 0; w < NWV; ++w) { win += wtot[w]; suf += (w > wid) ? wtot[w] : 0; }
    const bool valid = (g_hi0 <= GTMAX) && (need <= win);   // need>=1 iff g_hi0<=GTMAX
    int running = suf;                      // above bucket 2t+1
    if (running < need && need <= running + h1) { s_bstar = 2 * t + 1; s_above = running; }
    running += h1;                          // above bucket 2t
    if (running < need && need <= running + h0) { s_bstar = 2 * t;     s_above = running; }
    __syncthreads();   // B3

    float th = 0.f;
    bool done = false;   // block-uniform throughout
    if (valid) {
        const int bstar = s_bstar, above = s_above;
        const int cnum  = hist[bstar];      // block-uniform
        if (cnum <= 64) {
            // collect candidates by rescanning the LDS tile
            #pragma unroll
            for (int j = 0; j < V4; ++j) {
                float4 v = tile4[j * NT + t];
                float a[4] = {v.x, v.y, v.z, v.w};
                #pragma unroll
                for (int c = 0; c < 4; ++c) {
                    float x = a[c];
                    if (x > LO0 && x <= HI0 && bucket_of(x) == bstar) {
                        int pos = atomicAdd(&s_nc, 1); cands[pos] = x;
                    }
                }
            }
            __syncthreads();   // B4
            const int m = s_nc;             // == cnum, usually 1-2
            for (int i = t; i < m; i += NT) {
                float ci = cands[i];
                int gt = 0, eq = 0;
                for (int j2 = 0; j2 < m; ++j2) {
                    float cj = cands[j2];
                    gt += (cj > ci) ? 1 : 0; eq += (cj == ci) ? 1 : 0;
                }
                int gg = g_hi0 + above + gt;
                if (gg <= GTMAX && gg + eq >= GTMAX + 1) s_th = ci;
            }
            __syncthreads();   // B5
            th = s_th;
            done = true;
        }
    }
    if (!done) {
        // ---- Exact fallback (rare): value bisection on the LDS tile ----
        float lo = -1.0f, hiv = mv;
        int g_lo = HW, g_hiC = 0;
        bool degen = false;
        while (g_lo - g_hiC > 48) {
            float mid = 0.5f * (lo + hiv);
            if (!(mid > lo && mid < hiv)) { degen = true; break; }
            int cnt = 0;
            #pragma unroll
            for (int j = 0; j < V4; ++j) {
                float4 v = tile4[j * NT + t];
                cnt += (v.x > mid) + (v.y > mid) + (v.z > mid) + (v.w > mid);
            }
            #pragma unroll
            for (int off = 32; off > 0; off >>= 1) cnt += __shfl_down(cnt, off);
            if (lane == 0) wcnt[wid] = cnt;
            __syncthreads();
            int g = 0;
            #pragma unroll
            for (int w = 0; w < NWV; ++w) g += wcnt[w];
            __syncthreads();
            if (g >= GTMAX + 1) { lo = mid; g_lo = g; }
            else                { hiv = mid; g_hiC = g; }
        }
        if (degen) th = hiv;
        else {
            if (t == 0) s_nc = 0;
            __syncthreads();
            #pragma unroll
            for (int j = 0; j < V4; ++j) {
                float4 v = tile4[j * NT + t];
                float a[4] = {v.x, v.y, v.z, v.w};
                #pragma unroll
                for (int c2 = 0; c2 < 4; ++c2) {
                    float x = a[c2];
                    if (x > lo && x <= hiv) { int pos = atomicAdd(&s_nc, 1); if (pos < 64) cands[pos] = x; }
                }
            }
            __syncthreads();
            int m = s_nc; m = m > 64 ? 64 : m;
            for (int i = t; i < m; i += NT) {
                float ci = cands[i];
                int gt = 0, eq = 0;
                for (int j2 = 0; j2 < m; ++j2) {
                    float cj = cands[j2];
                    gt += (cj > ci) ? 1 : 0; eq += (cj == ci) ? 1 : 0;
                }
                int gg = g_hiC + gt;
                if (gg <= GTMAX && gg + eq >= GTMAX + 1) s_th = ci;
            }
            __syncthreads();
            th = s_th;
        }
    }

    // ---- Pass 2: mask from LDS tile (tgt > th), pred from regs; Gaussian inline.
    // g = exp(-d2/8) only within the 31x31 box (outside g<=1.3e-14; error ~1e-11).
    const int cyi = mi >> 7, cxi = mi & 127;
    float sum = 0.f;
    #pragma unroll
    for (int j = 0; j < V4; ++j) {
        float4 v = tile4[j * NT + t];
        const int base = (j * NT + t) * 4;
        float at[4] = {v.x, v.y, v.z, v.w};
        float ap[4] = {pv[j].x, pv[j].y, pv[j].z, pv[j].w};
        #pragma unroll
        for (int c = 0; c < 4; ++c) {
            if (at[c] > th) {
                const int idx = base + c;
                const int dy = (idx >> 7) - cyi, dx = (idx & 127) - cxi;
                float p = ap[c];
                if (dy >= -15 && dy <= 15 && dx >= -15 && dx <= 15) {
                    float g = __expf((float)(dy * dy + dx * dx) * -0.125f);
                    float d = p - g;
                    sum += d * d;
                } else {
                    sum += p * p;
                }
            }
        }
    }

    // ---- Block reduce, one plain store ----
    #pragma unroll
    for (int off = 32; off > 0; off >>= 1) sum += __shfl_down(sum, off);
    __syncthreads();                 // redf reuse guard
    if (lane == 0) redf[wid] = sum;
    __syncthreads();
    if (t == 0) {
        float s = 0.f;
        #pragma unroll
        for (int w = 0; w < NWV; ++w) s += redf[w];
        partial[bid] = s;
    }
}

__global__ __launch_bounds__(256) void wreg_final(
    const float* __restrict__ partial, float* __restrict__ out)
{
    __shared__ float red[4];
    const int t = threadIdx.x;
    float s = 0.f;
    for (int i = t; i < NSLICE; i += 256) s += partial[i];
    #pragma unroll
    for (int off = 32; off > 0; off >>= 1) s += __shfl_down(s, off);
    if ((t & 63) == 0) red[t >> 6] = s;
    __syncthreads();
    if (t == 0)
        out[0] = ((red[0] + red[1]) + (red[2] + red[3]))
                 * (1.0f / ((float)GTMAX * (float)NSLICE));  // / pxl_num / (B*K)
}

extern "C" void kernel_launch(void* const* d_in, const int* in_sizes, int n_in,
                              void* d_out, int out_size, void* d_ws, size_t ws_size,
                              hipStream_t stream)
{
    const float* pred = (const float*)d_in[0];   // "output" in reference
    const float* tgt  = (const float*)d_in[1];   // "target"
    float* partial = (float*)d_ws;               // 1088 floats scratch
    float* out     = (float*)d_out;

    wreg_fused<<<NSLICE, NT, 0, stream>>>(pred, tgt, partial);
    wreg_final<<<1, 256, 0, stream>>>(partial, out);
}

// Round 8
// 166.610 us; speedup vs baseline: 1.0728x; 1.0027x over previous
//
#include <hip/hip_runtime.h>

// Problem: B=64, K=17, H=128, W=128, RATIO=0.25, SIGMA=2.0
// Loss decomposition: (p-g)^2*[x>th] = p^2*[x>th] + (g^2-2pg)*[x>th], g nonzero only
// in the 31x31 box around argmax -> pred stream needs NO threshold: one fused pass.
constexpr int   HW     = 16384;
constexpr int   NT     = 512;            // threads per block; 1 block per slice
constexpr int   NWV    = 8;              // waves per block
constexpr int   V4     = 8;              // float4 chunks per thread per array
constexpr int   GTMAX  = 4096;           // #(v > thresh) for kthvalue rank 12288
constexpr int   NSLICE = 1088;           // 64*17
constexpr int   SLOTS  = 10;             // per-thread stash (lambda 1.12, P(ovf/launch)~2e-2)
constexpr int   SSTR   = 11;             // stash stride pad
constexpr int   BINS   = 1024;           // counting-refinement buckets
constexpr float LO0    = 0.735f;         // static bracket around 0.75-quantile of U(0,1)
constexpr float HI0    = 0.770f;         // runtime-validated; exact fallback otherwise
constexpr float BSCALE = (float)BINS / (HI0 - LO0);

__device__ __forceinline__ int bucket_of(float x) {
    int b = (int)((x - LO0) * BSCALE);   // monotone in x on (LO0, HI0]
    return b < 0 ? 0 : (b > BINS - 1 ? BINS - 1 : b);
}

// LDS ~50KB -> 3 blocks/CU; lb(512,6) -> 24 waves/CU cap.
__global__ __launch_bounds__(NT, 6) void wreg_fused(
    const float* __restrict__ pred,
    const float* __restrict__ tgt,
    float* __restrict__ partial)
{
    __shared__ int   cnt[BINS];           // 4 KB
    __shared__ float sval[NT * SSTR];     // 22.5 KB window tgt values
    __shared__ float spre[NT * SSTR];     // 22.5 KB window pred values
    __shared__ float redf[NWV];
    __shared__ int   redi[NWV];
    __shared__ int   whi[NWV], wwin[NWV], wovf[NWV], wcnt[NWV], wtot[NWV];
    __shared__ float cands[64];
    __shared__ int   s_nc, s_bstar, s_above;
    __shared__ float s_th;

    const int t = threadIdx.x, lane = t & 63, wid = t >> 6;
    const int bid = blockIdx.x;
    const float*  ts = tgt  + (size_t)bid * HW;
    const float*  ps = pred + (size_t)bid * HW;
    const float4* t4 = reinterpret_cast<const float4*>(ts);
    const float4* p4 = reinterpret_cast<const float4*>(ps);
    const int sbase = t * SSTR;

    for (int i = t; i < BINS; i += NT) cnt[i] = 0;
    if (t == 0) s_nc = 0;

    // ---- Fused streaming pass: tgt + pred chunk-interleaved, ZERO barriers inside.
    // 24 waves/CU each keep 2-4 chunk loads in flight -> continuous memory issue.
    float sum = 0.f;                      // masked p^2 accumulator (starts with x>HI0 part)
    float bmax = -1.f; int bmi = 0;
    int hic = 0, myn = 0;
    #pragma unroll
    for (int j = 0; j < V4; ++j) {
        float4 tv = t4[j * NT + t];
        float4 pv = p4[j * NT + t];
        const int base = (j * NT + t) * 4;
        float at[4] = {tv.x, tv.y, tv.z, tv.w};
        float ap[4] = {pv.x, pv.y, pv.z, pv.w};
        #pragma unroll
        for (int c = 0; c < 4; ++c) {
            float x = at[c], p = ap[c];
            if (x > bmax) { bmax = x; bmi = base + c; }   // per-thread idx increasing
            if (x > HI0) { sum += p * p; ++hic; }
            else if (x > LO0) {
                if (myn < SLOTS) { sval[sbase + myn] = x; spre[sbase + myn] = p; }
                ++myn;
            }
        }
    }
    const int mynv = myn > SLOTS ? SLOTS : myn;

    // ---- One combined block reduce: argmax + #(>HI0) + window count + overflow ----
    {
        float am = bmax; int ai = bmi;
        int rh = hic, rw = myn, ro = (myn > SLOTS) ? 1 : 0;
        #pragma unroll
        for (int off = 32; off > 0; off >>= 1) {
            float ov = __shfl_down(am, off); int ai2 = __shfl_down(ai, off);
            int o1 = __shfl_down(rh, off), o2 = __shfl_down(rw, off), o3 = __shfl_down(ro, off);
            if (ov > am || (ov == am && ai2 < ai)) { am = ov; ai = ai2; }
            rh += o1; rw += o2; ro |= o3;
        }
        if (lane == 0) { redf[wid] = am; redi[wid] = ai; whi[wid] = rh; wwin[wid] = rw; wovf[wid] = ro; }
    }
    __syncthreads();   // B1: orders cnt zeroing, s_nc, stash, wave arrays
    float mv = redf[0]; int mi = redi[0];
    int g_hi0 = 0, win = 0, anyovf = 0;
    #pragma unroll
    for (int w = 0; w < NWV; ++w) {
        if (redf[w] > mv || (redf[w] == mv && redi[w] < mi)) { mv = redf[w]; mi = redi[w]; }
        g_hi0 += whi[w]; win += wwin[w]; anyovf |= wovf[w];
    }
    const int need = (GTMAX + 1) - g_hi0;   // rank-from-top within the window
    const bool valid = (!anyovf) && (g_hi0 <= GTMAX) && (need <= win);

    float th = 0.f;
    bool done = false;   // block-uniform throughout

    if (valid) {
        // ---- Counting refinement: histogram stash, suffix-scan, exact tiny rank ----
        for (int k = 0; k < mynv; ++k)
            atomicAdd(&cnt[bucket_of(sval[sbase + k])], 1);
        __syncthreads();
        const int h0 = cnt[2 * t], h1 = cnt[2 * t + 1];
        const int lsum = h0 + h1;
        int incl = lsum;                        // wave suffix-inclusive scan
        #pragma unroll
        for (int off = 1; off < 64; off <<= 1) {
            int v = __shfl_down(incl, off);
            incl += (lane + off < 64) ? v : 0;
        }
        if (lane == 0) wtot[wid] = incl;        // wave total
        __syncthreads();
        int suf = incl - lsum;                  // count in strictly-higher buckets (my wave)
        #pragma unroll
        for (int w = 0; w < NWV; ++w) suf += (w > wid) ? wtot[w] : 0;
        int running = suf;                      // above bucket 2t+1
        if (running < need && need <= running + h1) { s_bstar = 2 * t + 1; s_above = running; }
        running += h1;                          // above bucket 2t
        if (running < need && need <= running + h0) { s_bstar = 2 * t;     s_above = running; }
        __syncthreads();
        const int bstar = s_bstar, above = s_above;
        const int cnum = cnt[bstar];            // block-uniform
        if (cnum <= 64) {
            for (int k = 0; k < mynv; ++k) {
                float x = sval[sbase + k];
                if (bucket_of(x) == bstar) { int pos = atomicAdd(&s_nc, 1); cands[pos] = x; }
            }
            __syncthreads();
            const int m = s_nc;                 // == cnum, usually 1-2
            for (int i = t; i < m; i += NT) {
                float ci = cands[i];
                int gt = 0, eq = 0;
                for (int j2 = 0; j2 < m; ++j2) {
                    float cj = cands[j2];
                    gt += (cj > ci) ? 1 : 0; eq += (cj == ci) ? 1 : 0;
                }
                int gg = g_hi0 + above + gt;
                if (gg <= GTMAX && gg + eq >= GTMAX + 1) s_th = ci;
            }
            __syncthreads();
            th = s_th;
            done = true;
        }
    }
    const bool fb = !done;
    if (fb) {
        // ---- Exact fallback (rare, ~2%/launch): bisection re-reading tgt (cache-warm) ----
        float lo = -1.0f, hi = mv;
        int g_lo = HW, g_hi = 0;
        bool degen = false;
        while (g_lo - g_hi > 48) {
            float mid = 0.5f * (lo + hi);
            if (!(mid > lo && mid < hi)) { degen = true; break; }
            int c2 = 0;
            for (int j = 0; j < V4; ++j) {
                float4 v = t4[j * NT + t];
                c2 += (v.x > mid) + (v.y > mid) + (v.z > mid) + (v.w > mid);
            }
            #pragma unroll
            for (int off = 32; off > 0; off >>= 1) c2 += __shfl_down(c2, off);
            if (lane == 0) wcnt[wid] = c2;
            __syncthreads();
            int g = 0;
            #pragma unroll
            for (int w = 0; w < NWV; ++w) g += wcnt[w];
            __syncthreads();
            if (g >= GTMAX + 1) { lo = mid; g_lo = g; }
            else                { hi = mid; g_hi = g; }
        }
        if (degen) th = hi;
        else {
            if (t == 0) s_nc = 0;
            __syncthreads();
            for (int j = 0; j < V4; ++j) {
                float4 v = t4[j * NT + t];
                float a[4] = {v.x, v.y, v.z, v.w};
                for (int c2 = 0; c2 < 4; ++c2) {
                    float x = a[c2];
                    if (x > lo && x <= hi) { int pos = atomicAdd(&s_nc, 1); if (pos < 64) cands[pos] = x; }
                }
            }
            __syncthreads();
            int m = s_nc; m = m > 64 ? 64 : m;
            for (int i = t; i < m; i += NT) {
                float ci = cands[i];
                int gt = 0, eq = 0;
                for (int j2 = 0; j2 < m; ++j2) {
                    float cj = cands[j2];
                    gt += (cj > ci) ? 1 : 0; eq += (cj == ci) ? 1 : 0;
                }
                int gg = g_hi + gt;
                if (gg <= GTMAX && gg + eq >= GTMAX + 1) s_th = ci;
            }
            __syncthreads();
            th = s_th;
        }
        // recompute masked p^2 from scratch (L3-warm re-read)
        sum = 0.f;
        for (int j = 0; j < V4; ++j) {
            float4 tv = t4[j * NT + t];
            float4 pv = p4[j * NT + t];
            float at[4] = {tv.x, tv.y, tv.z, tv.w};
            float ap[4] = {pv.x, pv.y, pv.z, pv.w};
            for (int c = 0; c < 4; ++c)
                if (at[c] > th) sum += ap[c] * ap[c];
        }
    } else {
        // window part: stash sweep with exact threshold
        for (int k = 0; k < mynv; ++k)
            if (sval[sbase + k] > th) { float p = spre[sbase + k]; sum += p * p; }
    }

    // ---- Box fixup: add (g^2 - 2pg) for masked elements in the 31x31 box.
    // Outside the box g<=1.3e-14 (error ~1e-11, same approx as all validated rounds).
    const int cyi = mi >> 7, cxi = mi & 127;
    for (int e = t; e < 961; e += NT) {
        const int by = e / 31, bx = e - 31 * by;
        const int y = cyi - 15 + by, x = cxi - 15 + bx;
        if (y >= 0 && y < 128 && x >= 0 && x < 128) {
            const int idx = (y << 7) + x;
            float tg = ts[idx];
            if (tg > th) {
                float p = ps[idx];
                float d2 = (float)((by - 15) * (by - 15) + (bx - 15) * (bx - 15));
                float g = __expf(d2 * -0.125f);
                sum += g * (g - 2.0f * p);    // (p-g)^2 - p^2
            }
        }
    }

    // ---- Block reduce, one plain store ----
    #pragma unroll
    for (int off = 32; off > 0; off >>= 1) sum += __shfl_down(sum, off);
    __syncthreads();                 // redf reuse guard
    if (lane == 0) redf[wid] = sum;
    __syncthreads();
    if (t == 0) {
        float s = 0.f;
        #pragma unroll
        for (int w = 0; w < NWV; ++w) s += redf[w];
        partial[bid] = s;
    }
}

__global__ __launch_bounds__(256) void wreg_final(
    const float* __restrict__ partial, float* __restrict__ out)
{
    __shared__ float red[4];
    const int t = threadIdx.x;
    float s = 0.f;
    for (int i = t; i < NSLICE; i += 256) s += partial[i];
    #pragma unroll
    for (int off = 32; off > 0; off >>= 1) s += __shfl_down(s, off);
    if ((t & 63) == 0) red[t >> 6] = s;
    __syncthreads();
    if (t == 0)
        out[0] = ((red[0] + red[1]) + (red[2] + red[3]))
                 * (1.0f / ((float)GTMAX * (float)NSLICE));  // / pxl_num / (B*K)
}

extern "C" void kernel_launch(void* const* d_in, const int* in_sizes, int n_in,
                              void* d_out, int out_size, void* d_ws, size_t ws_size,
                              hipStream_t stream)
{
    const float* pred = (const float*)d_in[0];   // "output" in reference
    const float* tgt  = (const float*)d_in[1];   // "target"
    float* partial = (float*)d_ws;               // 1088 floats scratch
    float* out     = (float*)d_out;

    wreg_fused<<<NSLICE, NT, 0, stream>>>(pred, tgt, partial);
    wreg_final<<<1, 256, 0, stream>>>(partial, out);
}